// Round 1
// baseline (254.970 us; speedup 1.0000x reference)
//
#include <hip/hip_runtime.h>

#define KFEAT 32
#define L1DIM 256
#define NB 16   // batch elements per block

__global__ __launch_bounds__(256, 4) void nnue_fused_kernel(
    const int* __restrict__ wf, const int* __restrict__ bf,
    const float* __restrict__ stm, const float* __restrict__ table,
    const float* __restrict__ ft_bias,
    const float* __restrict__ W1, const float* __restrict__ b1,
    const float* __restrict__ W2, const float* __restrict__ b2,
    const float* __restrict__ Wo, const float* __restrict__ bo,
    float* __restrict__ out)
{
    __shared__ int   feats[64];
    __shared__ float xbuf[512];
    __shared__ float y1s[32];

    const int t = threadIdx.x;
    const int j = t >> 3;   // output neuron of layer 1 (0..31)
    const int c = t & 7;    // chunk of the 512-dim input (0..7)

    // Stage this thread's W1 slice into registers (reused for NB batches).
    float w1r[64];
    const float* w1p = W1 + j * 512 + c * 64;
    #pragma unroll
    for (int ii = 0; ii < 64; ++ii) w1r[ii] = w1p[ii];

    const float ftb  = ft_bias[t];
    const float b1j  = b1[j];
    const float boS  = bo[0];

    for (int nb = 0; nb < NB; ++nb) {
        const int b = blockIdx.x * NB + nb;

        if (t < 32)       feats[t]      = wf[b * KFEAT + t];
        else if (t < 64)  feats[t]      = bf[b * KFEAT + (t - 32)];
        __syncthreads();

        // ---- Phase 1: embedding-bag gather (thread t owns dim t) ----
        float wa = ftb, ba = ftb;
        #pragma unroll 8
        for (int k = 0; k < KFEAT; ++k)
            wa += table[feats[k] * L1DIM + t];
        #pragma unroll 8
        for (int k = 0; k < KFEAT; ++k)
            ba += table[feats[KFEAT + k] * L1DIM + t];

        const float s = stm[b];
        float x0 = s * wa + (1.0f - s) * ba;   // wtm half
        float x1 = s * ba + (1.0f - s) * wa;   // btm half
        x0 = fminf(fmaxf(x0, 0.0f), 1.0f);
        x1 = fminf(fmaxf(x1, 0.0f), 1.0f);
        xbuf[t]       = x0;
        xbuf[t + 256] = x1;
        __syncthreads();

        // ---- Phase 2: layer 1 (512 -> 32), 8 partials per output ----
        float acc = 0.0f;
        const float* xb = &xbuf[c * 64];
        #pragma unroll
        for (int ii = 0; ii < 64; ++ii)
            acc = fmaf(w1r[ii], xb[ii], acc);
        acc += __shfl_xor(acc, 1);
        acc += __shfl_xor(acc, 2);
        acc += __shfl_xor(acc, 4);
        if (c == 0) {
            float y = acc + b1j;
            y1s[j] = fminf(fmaxf(y, 0.0f), 1.0f);
        }
        __syncthreads();

        // ---- Phase 3: layer 2 (32 -> 32) + output (32 -> 1) ----
        if (t < 32) {
            float a2 = b2[t];
            #pragma unroll
            for (int i = 0; i < 32; ++i)
                a2 = fmaf(y1s[i], W2[t * 32 + i], a2);
            a2 = fminf(fmaxf(a2, 0.0f), 1.0f);
            float p = a2 * Wo[t];
            p += __shfl_xor(p, 1);
            p += __shfl_xor(p, 2);
            p += __shfl_xor(p, 4);
            p += __shfl_xor(p, 8);
            p += __shfl_xor(p, 16);
            if (t == 0) out[b] = p + boS;
        }
        __syncthreads();  // protect feats/xbuf/y1s before next batch
    }
}

extern "C" void kernel_launch(void* const* d_in, const int* in_sizes, int n_in,
                              void* d_out, int out_size, void* d_ws, size_t ws_size,
                              hipStream_t stream) {
    const int*   wf      = (const int*)  d_in[0];   // white_features
    // d_in[1] = white_offsets (unused: uniform bags, offset = b*K)
    const int*   bf      = (const int*)  d_in[2];   // black_features
    // d_in[3] = black_offsets (unused)
    const float* stm     = (const float*)d_in[4];
    const float* table   = (const float*)d_in[5];
    const float* ft_bias = (const float*)d_in[6];
    const float* W1      = (const float*)d_in[7];
    const float* b1      = (const float*)d_in[8];
    const float* W2      = (const float*)d_in[9];
    const float* b2      = (const float*)d_in[10];
    const float* Wo      = (const float*)d_in[11];
    const float* bo      = (const float*)d_in[12];
    float*       out     = (float*)d_out;

    const int B = in_sizes[1];           // 16384 (offsets count)
    const int grid = B / NB;             // 1024 blocks

    nnue_fused_kernel<<<grid, 256, 0, stream>>>(
        wf, bf, stm, table, ft_bias, W1, b1, W2, b2, Wo, bo, out);
}

// Round 2
// 152.701 us; speedup vs baseline: 1.6697x; 1.6697x over previous
//
#include <hip/hip_runtime.h>

#define KFEAT 32
#define NB 8   // batch elements per block, processed in pairs (one bag per wave)

__device__ __forceinline__ float clip01(float v) {
    return fminf(fmaxf(v, 0.0f), 1.0f);
}

__global__ __launch_bounds__(256, 6) void nnue_fused_kernel(
    const int* __restrict__ wf, const int* __restrict__ bf,
    const float* __restrict__ stm, const float* __restrict__ table,
    const float* __restrict__ ft_bias,
    const float* __restrict__ W1, const float* __restrict__ b1,
    const float* __restrict__ W2, const float* __restrict__ b2,
    const float* __restrict__ Wo, const float* __restrict__ bo,
    float* __restrict__ out)
{
    __shared__ float4 accs[4][64];     // raw bag sums: [wave=(esub,side)][lane]
    __shared__ float  xs[2 * 4 * 132]; // mixed+clipped x, bank-padded groups of 32 float4
    __shared__ float  y1s[2][32];

    const int t    = threadIdx.x;
    const int l    = t & 63;
    const int w    = t >> 6;   // wave 0..3
    const int side = w & 1;    // 0=white, 1=black
    const int esub = w >> 1;   // element of the pair this wave gathers

    // Invariants hoisted out of the batch loop.
    const float4 ftb4 = reinterpret_cast<const float4*>(ft_bias)[l];
    const int*   fptr = side ? bf : wf;

    const int j = t >> 3;      // phase-2 output neuron 0..31
    const int c = t & 7;       // phase-2 chunk 0..7 (64 dims each)
    const float* w1p = W1 + j * 512 + c * 64;
    const float* x0p = &xs[(0 * 4 + (c >> 1)) * 132 + (c & 1) * 64];
    const float* x1p = &xs[(1 * 4 + (c >> 1)) * 132 + (c & 1) * 64];

    for (int it = 0; it < NB / 2; ++it) {
        const int b0 = blockIdx.x * NB + it * 2;

        // ---- Phase 1: embedding-bag gather; wave reads full 1KB row per load ----
        int idxv = fptr[(size_t)(b0 + esub) * KFEAT + (l & 31)];
        float4 acc = ftb4;
        #pragma unroll
        for (int k = 0; k < KFEAT; ++k) {
            const int row = __builtin_amdgcn_readfirstlane(__shfl(idxv, k, 64));
            const float4 v = reinterpret_cast<const float4*>(table)[(size_t)row * 64 + l];
            acc.x += v.x; acc.y += v.y; acc.z += v.z; acc.w += v.w;
        }
        accs[w][l] = acc;
        __syncthreads();

        // ---- Mixing + clip: x = crelu(s*wtm + (1-s)*btm), padded LDS store ----
        {
            const int e  = t >> 7;         // element of the pair
            const int hf = (t >> 6) & 1;   // which 256-dim half of x
            const int i  = t & 63;
            const float s  = stm[b0 + e];
            const float os = 1.0f - s;
            const float4 wa = accs[e * 2 + 0][i];
            const float4 ba = accs[e * 2 + 1][i];
            float4 x;
            if (hf == 0) {
                x.x = clip01(s * wa.x + os * ba.x);
                x.y = clip01(s * wa.y + os * ba.y);
                x.z = clip01(s * wa.z + os * ba.z);
                x.w = clip01(s * wa.w + os * ba.w);
            } else {
                x.x = clip01(s * ba.x + os * wa.x);
                x.y = clip01(s * ba.y + os * wa.y);
                x.z = clip01(s * ba.z + os * wa.z);
                x.w = clip01(s * ba.w + os * wa.w);
            }
            const int slot = hf * 64 + i;          // float4 slot 0..127
            const int g = slot >> 5, i4 = slot & 31;
            *reinterpret_cast<float4*>(&xs[(e * 4 + g) * 132 + i4 * 4]) = x;
        }
        __syncthreads();

        // ---- Phase 2: layer 1 (512 -> 32) for BOTH elements, shared W1 reads ----
        float a0 = 0.0f, a1 = 0.0f;
        #pragma unroll 16
        for (int ii = 0; ii < 64; ++ii) {
            const float wv = w1p[ii];
            a0 = fmaf(wv, x0p[ii], a0);
            a1 = fmaf(wv, x1p[ii], a1);
        }
        a0 += __shfl_xor(a0, 1); a0 += __shfl_xor(a0, 2); a0 += __shfl_xor(a0, 4);
        a1 += __shfl_xor(a1, 1); a1 += __shfl_xor(a1, 2); a1 += __shfl_xor(a1, 4);
        if (c == 0) {
            const float bj = b1[j];
            y1s[0][j] = clip01(a0 + bj);
            y1s[1][j] = clip01(a1 + bj);
        }
        __syncthreads();

        // ---- Phase 3: layer 2 (32 -> 32) + output head ----
        if (t < 64) {
            const int e = t >> 5, i = t & 31;
            float a2 = b2[i];
            #pragma unroll
            for (int k2 = 0; k2 < 32; ++k2)
                a2 = fmaf(y1s[e][k2], W2[i * 32 + k2], a2);
            a2 = clip01(a2);
            float p = a2 * Wo[i];
            p += __shfl_xor(p, 1);  p += __shfl_xor(p, 2);
            p += __shfl_xor(p, 4);  p += __shfl_xor(p, 8);
            p += __shfl_xor(p, 16);
            if (i == 0) out[b0 + e] = p + bo[0];
        }
        __syncthreads();  // protect accs/xs/y1s before next pair
    }
}

extern "C" void kernel_launch(void* const* d_in, const int* in_sizes, int n_in,
                              void* d_out, int out_size, void* d_ws, size_t ws_size,
                              hipStream_t stream) {
    const int*   wf      = (const int*)  d_in[0];
    const int*   bf      = (const int*)  d_in[2];
    const float* stm     = (const float*)d_in[4];
    const float* table   = (const float*)d_in[5];
    const float* ft_bias = (const float*)d_in[6];
    const float* W1      = (const float*)d_in[7];
    const float* b1      = (const float*)d_in[8];
    const float* W2      = (const float*)d_in[9];
    const float* b2      = (const float*)d_in[10];
    const float* Wo      = (const float*)d_in[11];
    const float* bo      = (const float*)d_in[12];
    float*       out     = (float*)d_out;

    const int B = in_sizes[1];     // 16384
    const int grid = B / NB;       // 2048 blocks

    nnue_fused_kernel<<<grid, 256, 0, stream>>>(
        wf, bf, stm, table, ft_bias, W1, b1, W2, b2, Wo, bo, out);
}